// Round 5
// baseline (570.972 us; speedup 1.0000x reference)
//
#include <hip/hip_runtime.h>
#include <hip/hip_bf16.h>
#include <math.h>

#define T_TOKENS 16384
#define DM 512
#define DFF 2048
#define NE 8
#define TOKT 64
#define FCH 256
#define NFC (DFF / FCH)   // 8
#define KCH 128
#define NKC (DM / KCH)    // 4

// out layout: Y [16384*512] | router_logits [16384*8] | entropy [1]
#define RL_OFF  ((size_t)T_TOKENS * DM)
#define ENT_OFF (RL_OFF + (size_t)T_TOKENS * NE)

typedef __attribute__((ext_vector_type(8))) short short8;
typedef __attribute__((ext_vector_type(4))) float f32x4;

__device__ __forceinline__ unsigned short f2bf(float f) {
    union { float f; unsigned u; } v; v.f = f;
    unsigned r = v.u + 0x7FFFu + ((v.u >> 16) & 1u);   // RNE
    return (unsigned short)(r >> 16);
}
__device__ __forceinline__ float bf2f(unsigned short h) {
    union { unsigned u; float f; } v; v.u = ((unsigned)h) << 16; return v.f;
}
__device__ __forceinline__ void atomAddF(float* p, float v) {
    __hip_atomic_fetch_add(p, v, __ATOMIC_RELAXED, __HIP_MEMORY_SCOPE_AGENT);
}

// global -> LDS direct DMA, 16B per lane. LDS dest = wave-uniform base + lane*16.
__device__ __forceinline__ void gl16(const void* g, void* l) {
    __builtin_amdgcn_global_load_lds(
        (const __attribute__((address_space(1))) unsigned*)(unsigned long long)g,
        (__attribute__((address_space(3))) unsigned*)(unsigned)(unsigned long long)l,
        16, 0, 0);
}

// ---------------- fp32 -> bf16 conversion ----------------
__global__ void cvt_kernel(const float* __restrict__ src, unsigned short* __restrict__ dst, size_t n4) {
    for (size_t i = blockIdx.x * (size_t)blockDim.x + threadIdx.x; i < n4;
         i += (size_t)gridDim.x * blockDim.x) {
        f32x4 v = ((const f32x4*)src)[i];
        unsigned short b0 = f2bf(v.x), b1 = f2bf(v.y), b2 = f2bf(v.z), b3 = f2bf(v.w);
        ((unsigned long long*)dst)[i] =
            (unsigned long long)b0 | ((unsigned long long)b1 << 16) |
            ((unsigned long long)b2 << 32) | ((unsigned long long)b3 << 48);
    }
}

// ---------------- router: 16 waves, 1 token per wave; also emits bf16 X copy ----------------
__global__ __launch_bounds__(1024)
void router_kernel(const float* __restrict__ x, const float* __restrict__ gw,
                   float* __restrict__ out, int* __restrict__ cursor,
                   int* __restrict__ slotlist, float* __restrict__ wgtlist,
                   float* __restrict__ entPartial, unsigned short* __restrict__ xbw) {
    __shared__ int   lcnt[NE];
    __shared__ int   lbase[NE];
    __shared__ float lent[16];
    __shared__ int   le[16][2];
    __shared__ int   lpos[16][2];
    __shared__ float lw[16][2];

    int tid = threadIdx.x;
    int wid = tid >> 6, lane = tid & 63;
    int t = blockIdx.x * 16 + wid;
    if (tid < NE) lcnt[tid] = 0;
    __syncthreads();

    const float* xr = x + (size_t)t * DM + lane * 8;
    f32x4 x0 = *(const f32x4*)xr;
    f32x4 x1 = *(const f32x4*)(xr + 4);

    if (xbw) {   // bf16 X copy (fused: X is already in registers)
        short8 v;
        v[0]=(short)f2bf(x0.x); v[1]=(short)f2bf(x0.y); v[2]=(short)f2bf(x0.z); v[3]=(short)f2bf(x0.w);
        v[4]=(short)f2bf(x1.x); v[5]=(short)f2bf(x1.y); v[6]=(short)f2bf(x1.z); v[7]=(short)f2bf(x1.w);
        *(short8*)(xbw + (size_t)t * DM + lane * 8) = v;
    }

    float logit[NE];
#pragma unroll
    for (int e = 0; e < NE; ++e) {
        const float* g = gw + e * DM + lane * 8;
        f32x4 g0 = *(const f32x4*)g;
        f32x4 g1 = *(const f32x4*)(g + 4);
        float p = x0.x*g0.x + x0.y*g0.y + x0.z*g0.z + x0.w*g0.w
                + x1.x*g1.x + x1.y*g1.y + x1.z*g1.z + x1.w*g1.w;
#pragma unroll
        for (int off = 32; off > 0; off >>= 1) p += __shfl_xor(p, off);
        logit[e] = p;
    }
    float m = logit[0];
#pragma unroll
    for (int e = 1; e < NE; ++e) m = fmaxf(m, logit[e]);
    float pr[NE]; float s = 0.f;
#pragma unroll
    for (int e = 0; e < NE; ++e) { pr[e] = expf(logit[e] - m); s += pr[e]; }
    float inv = 1.f / s;
    float ent = 0.f;
#pragma unroll
    for (int e = 0; e < NE; ++e) { pr[e] *= inv; ent -= pr[e] * logf(fmaxf(pr[e], 1e-6f)); }
    // top-2, first occurrence wins ties (jax top_k order)
    float p0 = -1.f, p1 = -1.f; int e0 = 0, e1 = 0;
#pragma unroll
    for (int e = 0; e < NE; ++e) {
        float p = pr[e];
        if (p > p0)      { p1 = p0; e1 = e0; p0 = p; e0 = e; }
        else if (p > p1) { p1 = p;  e1 = e; }
    }
    float wsum = p0 + p1;

    if (lane == 0) {
        lent[wid] = ent;
        le[wid][0] = e0; le[wid][1] = e1;
        lw[wid][0] = p0 / wsum; lw[wid][1] = p1 / wsum;
        lpos[wid][0] = atomicAdd(&lcnt[e0], 1);
        lpos[wid][1] = atomicAdd(&lcnt[e1], 1);
    }
    float myLogit = 0.f;
#pragma unroll
    for (int e = 0; e < NE; ++e) if (lane == e) myLogit = logit[e];
    if (lane < NE) out[RL_OFF + (size_t)t * NE + lane] = myLogit;

    __syncthreads();
    if (tid < NE) lbase[tid] = atomicAdd(cursor + tid, lcnt[tid]);
    __syncthreads();
    if (tid < 16) {
        int a0 = le[tid][0], a1 = le[tid][1];
        int tt = blockIdx.x * 16 + tid;
        int q0 = lbase[a0] + lpos[tid][0];
        int q1 = lbase[a1] + lpos[tid][1];
        slotlist[a0 * T_TOKENS + q0] = tt * 2;     wgtlist[a0 * T_TOKENS + q0] = lw[tid][0];
        slotlist[a1 * T_TOKENS + q1] = tt * 2 + 1; wgtlist[a1 * T_TOKENS + q1] = lw[tid][1];
    }
    if (tid == 0) {
        float sum = 0.f;
#pragma unroll
        for (int w = 0; w < 16; ++w) sum += lent[w];
        entPartial[blockIdx.x] = sum;
    }
}

__global__ void ent_reduce(const float* __restrict__ part, float* __restrict__ out) {
    __shared__ float s[16];
    int tid = threadIdx.x;
    float v = part[tid];
#pragma unroll
    for (int off = 32; off > 0; off >>= 1) v += __shfl_xor(v, off);
    if ((tid & 63) == 0) s[tid >> 6] = v;
    __syncthreads();
    if (tid == 0) {
        float tot = 0.f;
#pragma unroll
        for (int w = 0; w < 16; ++w) tot += s[w];
        out[ENT_OFF] = tot * (1.0f / T_TOKENS);
    }
}

// ---------------- grouped fused FFN ----------------
// 64-token tile x 1 expert per block, 512 threads = 8 waves.
// LDS = 64 KB exactly (X chunk dbuf 2x16KB + Hs 32KB) -> 2 blocks/CU, 4 waves/SIMD.
// X chunks DMA'd via global_load_lds (swizzle via pre-permuted per-lane source col).
// Stage1 swapped mfma(W1,X) -> GELU b64 -> Hs -> stage2 mfma(H,W2).
template <int XB, int SLOT>
__global__ __launch_bounds__(512, 4)
void ffn_kernel(const float* __restrict__ x, const unsigned short* __restrict__ xb,
                const unsigned short* __restrict__ w1b, const unsigned short* __restrict__ w2b,
                const int* __restrict__ cursor, const int* __restrict__ slotlist,
                const float* __restrict__ wgtlist,
                unsigned short* __restrict__ ybuf, float* __restrict__ out) {
    __shared__ char XcB[2][TOKT * KCH * 2];   // 2 x 16 KB, row stride 256 B, swizzled
    __shared__ char HsB[TOKT * FCH * 2];      // 32 KB, row stride 512 B, swizzled

    int e   = blockIdx.x & 7;                 // expert == XCD for L2 pinning
    int cnt = cursor[e];
    int tid = threadIdx.x;
    int wid = tid >> 6, lane = tid & 63;
    int l16 = lane & 15, lg = lane >> 4;
    int swz = (l16 & 7) << 4;

    const unsigned short* w1e = w1b + (size_t)e * DFF * DM;
    const unsigned short* w2e = w2b + (size_t)e * DM * DFF;
    const int*   sl = slotlist + e * T_TOKENS;
    const float* wl = wgtlist  + e * T_TOKENS;

    // staging geometry: lane covers rows srow and srow+32, 16B slot = lane&15
    int srow = (wid << 2) + (lane >> 4);      // 0..31
    int slot = lane & 15;
    int step = (gridDim.x >> 3) * TOKT;

#pragma unroll 1
    for (int t0 = (blockIdx.x >> 3) * TOKT; t0 < cnt; t0 += step) {
        int i0 = t0 + srow, i1 = i0 + 32;
        int tok0 = sl[(i0 < cnt) ? i0 : t0] >> 1;
        int tok1 = sl[(i1 < cnt) ? i1 : t0] >> 1;
        // source pointers (bf16 path: column pre-permuted for swizzled LDS layout)
        const unsigned short* s0 = xb + (size_t)tok0 * DM + ((slot ^ (srow & 7)) << 3);
        const unsigned short* s1 = xb + (size_t)tok1 * DM + ((slot ^ (srow & 7)) << 3);
        const float* xf0 = x + (size_t)tok0 * DM + (slot << 3);
        const float* xf1 = x + (size_t)tok1 * DM + (slot << 3);

        // ---- prologue: stage chunk 0 into buf 0 ----
        if constexpr (XB == 1) {
            gl16(s0, XcB[0] + (wid << 10));
            gl16(s1, XcB[0] + (wid << 10) + 8192);
        } else {
#pragma unroll
            for (int u = 0; u < 2; ++u) {
                int row = srow + u * 32;
                const float* sp = (u ? xf1 : xf0);
                f32x4 a = *(const f32x4*)sp, b = *(const f32x4*)(sp + 4);
                short8 v;
                v[0]=(short)f2bf(a.x); v[1]=(short)f2bf(a.y); v[2]=(short)f2bf(a.z); v[3]=(short)f2bf(a.w);
                v[4]=(short)f2bf(b.x); v[5]=(short)f2bf(b.y); v[6]=(short)f2bf(b.z); v[7]=(short)f2bf(b.w);
                *(short8*)(XcB[0] + row * 256 + ((slot << 4) ^ ((row & 7) << 4))) = v;
            }
        }
        __syncthreads();

        f32x4 Yacc[4][4] = {};   // [tt][gt] : 64 tokens x 64 g-cols per wave

#pragma unroll 1
        for (int fc = 0; fc < NFC; ++fc) {
            f32x4 Hacc[2][4] = {};   // [ft][tt] swapped: D[f][token]
#pragma unroll
            for (int kc = 0; kc < NKC; ++kc) {
                char* rbuf = XcB[kc & 1];
                char* wbuf = XcB[(kc & 1) ^ 1];
                // issue next-chunk DMA (in flight across this phase's MFMAs)
                if (kc < NKC - 1 || fc < NFC - 1) {
                    int nkc = (kc + 1) & 3;
                    if constexpr (XB == 1) {
                        gl16(s0 + nkc * KCH, wbuf + (wid << 10));
                        gl16(s1 + nkc * KCH, wbuf + (wid << 10) + 8192);
                    } else {
#pragma unroll
                        for (int u = 0; u < 2; ++u) {
                            int row = srow + u * 32;
                            const float* sp = (u ? xf1 : xf0) + nkc * KCH;
                            f32x4 a = *(const f32x4*)sp, b = *(const f32x4*)(sp + 4);
                            short8 v;
                            v[0]=(short)f2bf(a.x); v[1]=(short)f2bf(a.y); v[2]=(short)f2bf(a.z); v[3]=(short)f2bf(a.w);
                            v[4]=(short)f2bf(b.x); v[5]=(short)f2bf(b.y); v[6]=(short)f2bf(b.z); v[7]=(short)f2bf(b.w);
                            *(short8*)(wbuf + row * 256 + ((slot << 4) ^ ((row & 7) << 4))) = v;
                        }
                    }
                }
                // stage1 MFMAs on chunk kc
                const unsigned short* w1p = w1e + (size_t)(fc * FCH + wid * 32 + l16) * DM
                                            + kc * KCH + lg * 8;
#pragma unroll
                for (int ks = 0; ks < 4; ++ks) {
                    short8 a0 = *(const short8*)(w1p + ks * 32);
                    short8 a1 = *(const short8*)(w1p + 16 * DM + ks * 32);
#pragma unroll
                    for (int tt = 0; tt < 4; ++tt) {
                        int row = tt * 16 + l16;
                        short8 xfr = *(const short8*)(rbuf + row * 256 + ((ks * 64 + lg * 16) ^ swz));
                        Hacc[0][tt] = __builtin_amdgcn_mfma_f32_16x16x32_bf16(a0, xfr, Hacc[0][tt], 0, 0, 0);
                        Hacc[1][tt] = __builtin_amdgcn_mfma_f32_16x16x32_bf16(a1, xfr, Hacc[1][tt], 0, 0, 0);
                    }
                }
                __syncthreads();   // DMA drained (vmcnt0) + all waves done reading rbuf
            }
            // ---- GELU -> Hs (b64, 4 consecutive f per lane); Hs safe: 4 barriers since stage2(fc-1) ----
#pragma unroll
            for (int ft = 0; ft < 2; ++ft)
#pragma unroll
            for (int tt = 0; tt < 4; ++tt) {
                f32x4 h = Hacc[ft][tt];
                unsigned long long pk = 0;
#pragma unroll
                for (int r = 0; r < 4; ++r) {
                    float g = 0.5f * h[r] * (1.0f + erff(h[r] * 0.70710678118f));
                    pk |= (unsigned long long)f2bf(g) << (r * 16);
                }
                int token = tt * 16 + l16;
                int f2 = wid * 64 + ft * 32 + lg * 8;   // f_local byte offset
                *(unsigned long long*)(HsB + token * 512 + (f2 ^ swz)) = pk;
            }
            __syncthreads();
            // ---- stage2: Y[token][g] += H * W2^T ----
            const unsigned short* w2p = w2e + (size_t)(wid * 64 + l16) * DFF + fc * FCH + lg * 8;
#pragma unroll
            for (int ks = 0; ks < 8; ++ks) {
                short8 b0 = *(const short8*)(w2p + ks * 32);
                short8 b1 = *(const short8*)(w2p + (size_t)16 * DFF + ks * 32);
                short8 b2 = *(const short8*)(w2p + (size_t)32 * DFF + ks * 32);
                short8 b3 = *(const short8*)(w2p + (size_t)48 * DFF + ks * 32);
#pragma unroll
                for (int tt = 0; tt < 4; ++tt) {
                    int row = tt * 16 + l16;
                    short8 af = *(const short8*)(HsB + row * 512 + ((ks * 64 + lg * 16) ^ swz));
                    Yacc[tt][0] = __builtin_amdgcn_mfma_f32_16x16x32_bf16(af, b0, Yacc[tt][0], 0, 0, 0);
                    Yacc[tt][1] = __builtin_amdgcn_mfma_f32_16x16x32_bf16(af, b1, Yacc[tt][1], 0, 0, 0);
                    Yacc[tt][2] = __builtin_amdgcn_mfma_f32_16x16x32_bf16(af, b2, Yacc[tt][2], 0, 0, 0);
                    Yacc[tt][3] = __builtin_amdgcn_mfma_f32_16x16x32_bf16(af, b3, Yacc[tt][3], 0, 0, 0);
                }
            }
            // no barrier: next fc's kc-loop barriers order Hs/Xc reuse
        }
        // ---- epilogue: scale + store ----
#pragma unroll
        for (int tt = 0; tt < 4; ++tt)
#pragma unroll
        for (int r = 0; r < 4; ++r) {
            int row = tt * 16 + lg * 4 + r;
            int idx = t0 + row;
            if (idx < cnt) {
                int entry = sl[idx];
                float wgt = wl[idx];
                if constexpr (SLOT == 1) {
                    unsigned short* dst = ybuf + (size_t)entry * DM + wid * 64;
#pragma unroll
                    for (int gt = 0; gt < 4; ++gt)
                        dst[gt * 16 + l16] = f2bf(Yacc[tt][gt][r] * wgt);
                } else {
                    float* dst = out + (size_t)(entry >> 1) * DM + wid * 64;
#pragma unroll
                    for (int gt = 0; gt < 4; ++gt)
                        atomAddF(dst + gt * 16 + l16, Yacc[tt][gt][r] * wgt);
                }
            }
        }
    }
}

// ---------------- combine: out[t] = Ybuf[2t] + Ybuf[2t+1] ----------------
__global__ __launch_bounds__(256)
void combine_kernel(const unsigned short* __restrict__ ybuf, float* __restrict__ out) {
    int gid = blockIdx.x * 256 + threadIdx.x;
    int t = gid >> 6, c8 = (gid & 63) * 8;
    const unsigned short* r0 = ybuf + ((size_t)t * 2) * DM + c8;
    short8 a = *(const short8*)r0;
    short8 b = *(const short8*)(r0 + DM);
    float* o = out + (size_t)t * DM + c8;
    f32x4 v0, v1;
    v0.x = bf2f((unsigned short)a[0]) + bf2f((unsigned short)b[0]);
    v0.y = bf2f((unsigned short)a[1]) + bf2f((unsigned short)b[1]);
    v0.z = bf2f((unsigned short)a[2]) + bf2f((unsigned short)b[2]);
    v0.w = bf2f((unsigned short)a[3]) + bf2f((unsigned short)b[3]);
    v1.x = bf2f((unsigned short)a[4]) + bf2f((unsigned short)b[4]);
    v1.y = bf2f((unsigned short)a[5]) + bf2f((unsigned short)b[5]);
    v1.z = bf2f((unsigned short)a[6]) + bf2f((unsigned short)b[6]);
    v1.w = bf2f((unsigned short)a[7]) + bf2f((unsigned short)b[7]);
    *(f32x4*)o = v0;
    *(f32x4*)(o + 4) = v1;
}

extern "C" void kernel_launch(void* const* d_in, const int* in_sizes, int n_in,
                              void* d_out, int out_size, void* d_ws, size_t ws_size,
                              hipStream_t stream) {
    const float* x  = (const float*)d_in[0];
    const float* gw = (const float*)d_in[1];
    const float* w1 = (const float*)d_in[2];
    const float* w2 = (const float*)d_in[3];
    float* out = (float*)d_out;
    char* ws = (char*)d_ws;

    const size_t W1N = (size_t)NE * DFF * DM;
    const size_t W2N = (size_t)NE * DM * DFF;
    unsigned short* w1b = (unsigned short*)ws;
    unsigned short* w2b = w1b + W1N;
    size_t off = (W1N + W2N) * 2;                       // 32 MiB
    int*   cursor   = (int*)(ws + off);   off += 256;
    int*   slotlist = (int*)(ws + off);   off += (size_t)NE * T_TOKENS * 4;
    float* wgtlist  = (float*)(ws + off); off += (size_t)NE * T_TOKENS * 4;
    float* entPart  = (float*)(ws + off); off += 8192;
    unsigned short* xbb = (unsigned short*)(ws + off); off += (size_t)T_TOKENS * DM * 2;
    size_t needB = off;
    unsigned short* ybuf = (unsigned short*)(ws + off); off += (size_t)T_TOKENS * 2 * DM * 2;
    size_t needA = off;

    int tier = (ws_size >= needA) ? 2 : ((ws_size >= needB) ? 1 : 0);

    hipMemsetAsync(cursor, 0, 64, stream);
    if (tier < 2) hipMemsetAsync(out, 0, RL_OFF * sizeof(float), stream);

    cvt_kernel<<<2048, 256, 0, stream>>>(w1, w1b, W1N / 4);
    cvt_kernel<<<2048, 256, 0, stream>>>(w2, w2b, W2N / 4);

    router_kernel<<<T_TOKENS / 16, 1024, 0, stream>>>(x, gw, out, cursor, slotlist, wgtlist,
                                                      entPart, tier >= 1 ? xbb : nullptr);
    ent_reduce<<<1, 1024, 0, stream>>>(entPart, out);

    if (tier == 2) {
        ffn_kernel<1, 1><<<NE * 64, 512, 0, stream>>>(x, xbb, w1b, w2b, cursor, slotlist, wgtlist, ybuf, out);
        combine_kernel<<<(T_TOKENS * DM / 8) / 256, 256, 0, stream>>>(ybuf, out);
    } else if (tier == 1) {
        ffn_kernel<1, 0><<<NE * 64, 512, 0, stream>>>(x, xbb, w1b, w2b, cursor, slotlist, wgtlist, nullptr, out);
    } else {
        ffn_kernel<0, 0><<<NE * 64, 512, 0, stream>>>(x, nullptr, w1b, w2b, cursor, slotlist, wgtlist, nullptr, out);
    }
}

// Round 7
// 439.615 us; speedup vs baseline: 1.2988x; 1.2988x over previous
//
#include <hip/hip_runtime.h>
#include <hip/hip_bf16.h>
#include <math.h>

#define T_TOKENS 16384
#define DM 512
#define DFF 2048
#define NE 8
#define TOKT 64
#define FCH 256
#define NFC (DFF / FCH)   // 8

// out layout: Y [16384*512] | router_logits [16384*8] | entropy [1]
#define RL_OFF  ((size_t)T_TOKENS * DM)
#define ENT_OFF (RL_OFF + (size_t)T_TOKENS * NE)

typedef __attribute__((ext_vector_type(8))) short short8;
typedef __attribute__((ext_vector_type(4))) float f32x4;

__device__ __forceinline__ unsigned short f2bf(float f) {
    union { float f; unsigned u; } v; v.f = f;
    unsigned r = v.u + 0x7FFFu + ((v.u >> 16) & 1u);   // RNE
    return (unsigned short)(r >> 16);
}
__device__ __forceinline__ float bf2f(unsigned short h) {
    union { unsigned u; float f; } v; v.u = ((unsigned)h) << 16; return v.f;
}
__device__ __forceinline__ void atomAddF(float* p, float v) {
    __hip_atomic_fetch_add(p, v, __ATOMIC_RELAXED, __HIP_MEMORY_SCOPE_AGENT);
}
// fast GELU: 0.5x(1+tanh(0.79788456(x+0.044715x^3))) = x*sigmoid(1.59576912(x+0.044715x^3))
// abs err vs exact-erf gelu < ~1e-3, below bf16 quantization of H.
__device__ __forceinline__ float gelu_f(float x) {
    float z = 1.5957691216f * x * (1.0f + 0.044715f * x * x);
    return x / (1.0f + __expf(-z));
}

// global -> LDS direct DMA, 16B per lane. LDS dest = wave-uniform base + lane*16.
__device__ __forceinline__ void gl16(const void* g, void* l) {
    __builtin_amdgcn_global_load_lds(
        (const __attribute__((address_space(1))) unsigned*)(unsigned long long)g,
        (__attribute__((address_space(3))) unsigned*)(unsigned)(unsigned long long)l,
        16, 0, 0);
}

#define MFMA16(A, B, C) __builtin_amdgcn_mfma_f32_16x16x32_bf16(A, B, C, 0, 0, 0)

// ---------------- fp32 -> bf16 conversion ----------------
__global__ void cvt_kernel(const float* __restrict__ src, unsigned short* __restrict__ dst, size_t n4) {
    for (size_t i = blockIdx.x * (size_t)blockDim.x + threadIdx.x; i < n4;
         i += (size_t)gridDim.x * blockDim.x) {
        f32x4 v = ((const f32x4*)src)[i];
        unsigned short b0 = f2bf(v.x), b1 = f2bf(v.y), b2 = f2bf(v.z), b3 = f2bf(v.w);
        ((unsigned long long*)dst)[i] =
            (unsigned long long)b0 | ((unsigned long long)b1 << 16) |
            ((unsigned long long)b2 << 32) | ((unsigned long long)b3 << 48);
    }
}

// ---------------- router: 16 waves, 1 token per wave; also emits bf16 X copy ----------------
__global__ __launch_bounds__(1024)
void router_kernel(const float* __restrict__ x, const float* __restrict__ gw,
                   float* __restrict__ out, int* __restrict__ cursor,
                   int* __restrict__ slotlist, float* __restrict__ wgtlist,
                   float* __restrict__ entPartial, unsigned short* __restrict__ xbw) {
    __shared__ int   lcnt[NE];
    __shared__ int   lbase[NE];
    __shared__ float lent[16];
    __shared__ int   le[16][2];
    __shared__ int   lpos[16][2];
    __shared__ float lw[16][2];

    int tid = threadIdx.x;
    int wid = tid >> 6, lane = tid & 63;
    int t = blockIdx.x * 16 + wid;
    if (tid < NE) lcnt[tid] = 0;
    __syncthreads();

    const float* xr = x + (size_t)t * DM + lane * 8;
    f32x4 x0 = *(const f32x4*)xr;
    f32x4 x1 = *(const f32x4*)(xr + 4);

    if (xbw) {   // bf16 X copy fused (X already in registers)
        short8 v;
        v[0]=(short)f2bf(x0.x); v[1]=(short)f2bf(x0.y); v[2]=(short)f2bf(x0.z); v[3]=(short)f2bf(x0.w);
        v[4]=(short)f2bf(x1.x); v[5]=(short)f2bf(x1.y); v[6]=(short)f2bf(x1.z); v[7]=(short)f2bf(x1.w);
        *(short8*)(xbw + (size_t)t * DM + lane * 8) = v;
    }

    float logit[NE];
#pragma unroll
    for (int e = 0; e < NE; ++e) {
        const float* g = gw + e * DM + lane * 8;
        f32x4 g0 = *(const f32x4*)g;
        f32x4 g1 = *(const f32x4*)(g + 4);
        float p = x0.x*g0.x + x0.y*g0.y + x0.z*g0.z + x0.w*g0.w
                + x1.x*g1.x + x1.y*g1.y + x1.z*g1.z + x1.w*g1.w;
#pragma unroll
        for (int off = 32; off > 0; off >>= 1) p += __shfl_xor(p, off);
        logit[e] = p;
    }
    float m = logit[0];
#pragma unroll
    for (int e = 1; e < NE; ++e) m = fmaxf(m, logit[e]);
    float pr[NE]; float s = 0.f;
#pragma unroll
    for (int e = 0; e < NE; ++e) { pr[e] = expf(logit[e] - m); s += pr[e]; }
    float inv = 1.f / s;
    float ent = 0.f;
#pragma unroll
    for (int e = 0; e < NE; ++e) { pr[e] *= inv; ent -= pr[e] * logf(fmaxf(pr[e], 1e-6f)); }
    // top-2, first occurrence wins ties (jax top_k order)
    float p0 = -1.f, p1 = -1.f; int e0 = 0, e1 = 0;
#pragma unroll
    for (int e = 0; e < NE; ++e) {
        float p = pr[e];
        if (p > p0)      { p1 = p0; e1 = e0; p0 = p; e0 = e; }
        else if (p > p1) { p1 = p;  e1 = e; }
    }
    float wsum = p0 + p1;

    if (lane == 0) {
        lent[wid] = ent;
        le[wid][0] = e0; le[wid][1] = e1;
        lw[wid][0] = p0 / wsum; lw[wid][1] = p1 / wsum;
        lpos[wid][0] = atomicAdd(&lcnt[e0], 1);
        lpos[wid][1] = atomicAdd(&lcnt[e1], 1);
    }
    float myLogit = 0.f;
#pragma unroll
    for (int e = 0; e < NE; ++e) if (lane == e) myLogit = logit[e];
    if (lane < NE) out[RL_OFF + (size_t)t * NE + lane] = myLogit;

    __syncthreads();
    if (tid < NE) lbase[tid] = atomicAdd(cursor + tid, lcnt[tid]);
    __syncthreads();
    if (tid < 16) {
        int a0 = le[tid][0], a1 = le[tid][1];
        int tt = blockIdx.x * 16 + tid;
        int q0 = lbase[a0] + lpos[tid][0];
        int q1 = lbase[a1] + lpos[tid][1];
        slotlist[a0 * T_TOKENS + q0] = tt * 2;     wgtlist[a0 * T_TOKENS + q0] = lw[tid][0];
        slotlist[a1 * T_TOKENS + q1] = tt * 2 + 1; wgtlist[a1 * T_TOKENS + q1] = lw[tid][1];
    }
    if (tid == 0) {
        float sum = 0.f;
#pragma unroll
        for (int w = 0; w < 16; ++w) sum += lent[w];
        entPartial[blockIdx.x] = sum;
    }
}

__global__ void ent_reduce(const float* __restrict__ part, float* __restrict__ out) {
    __shared__ float s[16];
    int tid = threadIdx.x;
    float v = part[tid];
#pragma unroll
    for (int off = 32; off > 0; off >>= 1) v += __shfl_xor(v, off);
    if ((tid & 63) == 0) s[tid >> 6] = v;
    __syncthreads();
    if (tid == 0) {
        float tot = 0.f;
#pragma unroll
        for (int w = 0; w < 16; ++w) tot += s[w];
        out[ENT_OFF] = tot * (1.0f / T_TOKENS);
    }
}

// ---------------- grouped fused FFN, m97-style LDS slab pipeline ----------------
// 64-token tile x 1 expert per block, 512 thr = 8 waves, LDS 128 KB:
//   Xs [64 tok][512 k] bf16 (64 KB, R4-proven swizzle),
//   Wring: 2 x 16 KB slab double-buffer (W1 slab [256 f][32 k], W2 slab [256 g][32 f]),
//   Hs [64 tok][256 f] bf16 (32 KB, R4-proven swizzle).
// 256 phases/tile; each phase: issue DMA of slab q+1 (global_load_lds, pre-swizzled
// per-lane source, linear LDS dest) -> 8 MFMAs from slab q -> __syncthreads (drains DMA).
// One slab always in flight; no manual vmcnt, no register rings.
template <int XB, int SLOT>
__global__ __launch_bounds__(512, 2)
void ffn_kernel(const float* __restrict__ x, const unsigned short* __restrict__ xb,
                const unsigned short* __restrict__ w1b, const unsigned short* __restrict__ w2b,
                const int* __restrict__ cursor, const int* __restrict__ slotlist,
                const float* __restrict__ wgtlist,
                unsigned short* __restrict__ ybuf, float* __restrict__ out) {
    __shared__ char XsB[TOKT * DM * 2];     // 64 KB
    __shared__ char Wring[2][16384];        // 32 KB
    __shared__ char HsB[TOKT * FCH * 2];    // 32 KB

    int e   = blockIdx.x & 7;               // expert == XCD for L2 pinning
    int cnt = cursor[e];
    int tid = threadIdx.x;
    int wid = tid >> 6, lane = tid & 63;
    int l16 = lane & 15, lg = lane >> 4;
    int swz = (l16 & 7) << 4;

    const char* w1e = (const char*)(w1b + (size_t)e * DFF * DM);
    const char* w2e = (const char*)(w2b + (size_t)e * DM * DFF);
    const int*   sl = slotlist + e * T_TOKENS;
    const float* wl = wgtlist  + e * T_TOKENS;

    // slab DMA: sA in [0,31]: sA<16 -> W1(fc, ks=sA) slab [256 f][32 k];
    //           sA>=16 -> W2(fc, fs=(sA-16)>>1, h=(sA-16)&1) slab [256 g][32 f].
    // LDS unit U holds logical 16B-unit m = (U ^ (U>>3)) & 3 of row r = U>>2
    // (i.e. stored m' = (m ^ (r>>1)) & 3 -> 2-way-max bank aliasing on reads).
    auto issue_slab = [&](int fcA, int sA) {
        char* dst = Wring[sA & 1];
#pragma unroll
        for (int j = 0; j < 2; ++j) {
            int U = wid * 64 + j * 512 + lane;
            int r = U >> 2;
            int ml = (U ^ (U >> 3)) & 3;
            const char* src;
            if (sA < 16) {
                src = w1e + (size_t)(fcA * 256 + r) * 1024 + sA * 64 + (ml << 4);
            } else {
                int t2 = sA - 16, fs = t2 >> 1, h = t2 & 1;
                src = w2e + (size_t)(h * 256 + r) * 4096 + fcA * 512 + fs * 64 + (ml << 4);
            }
            gl16(src, dst + (size_t)(wid * 64 + j * 512) * 16);
        }
    };
    // read a weight fragment: row rl (f or g local 0..255), k-part = lg
    auto wfrag = [&](const char* wb, int rl) -> short8 {
        return *(const short8*)(wb + ((rl * 4 + ((lg ^ (rl >> 1)) & 3)) << 4));
    };

    int step = (gridDim.x >> 3) * TOKT;
#pragma unroll 1
    for (int t0 = (blockIdx.x >> 3) * TOKT; t0 < cnt; t0 += step) {
        // ---- stage X once (R4-proven): 4096 x 16B units, 8 per thread ----
#pragma unroll
        for (int it = 0; it < 8; ++it) {
            int u = tid + it * 512;
            int row = u >> 6, c16 = u & 63;
            int idx = t0 + row;
            int sidx = (idx < cnt) ? idx : t0;
            int t = sl[sidx] >> 1;
            short8 v;
            if constexpr (XB == 1) {
                v = *(const short8*)(xb + (size_t)t * DM + c16 * 8);
            } else {
                const float* src = x + (size_t)t * DM + c16 * 8;
                f32x4 a = *(const f32x4*)src, b = *(const f32x4*)(src + 4);
                v[0]=(short)f2bf(a.x); v[1]=(short)f2bf(a.y); v[2]=(short)f2bf(a.z); v[3]=(short)f2bf(a.w);
                v[4]=(short)f2bf(b.x); v[5]=(short)f2bf(b.y); v[6]=(short)f2bf(b.z); v[7]=(short)f2bf(b.w);
            }
            *(short8*)(XsB + row * 1024 + ((c16 << 4) ^ ((row & 7) << 4))) = v;
        }
        issue_slab(0, 0);    // prologue: slab 0 in flight
        __syncthreads();     // drains staging writes + slab-0 DMA

        f32x4 Yacc[4][4] = {};   // [tt][gt], gt = h*2+ct -> g = (gt>>1)*256 + wid*32 + (gt&1)*16 + l16

#pragma unroll 1
        for (int fc = 0; fc < NFC; ++fc) {
            f32x4 Hacc[2][4] = {};   // [ct][tt] swapped: D[f][tok], wave f-window = wid*32
            // ---- stage1: 16 phases, one W1 k-slab each ----
#pragma unroll
            for (int s = 0; s < 16; ++s) {
                issue_slab(fc, s + 1);                  // s=15 -> W2 slab (fs0,h0) of this fc
                const char* wb = Wring[s & 1];
                int f0 = wid * 32 + l16;
                short8 a0 = wfrag(wb, f0);
                short8 a1 = wfrag(wb, f0 + 16);
#pragma unroll
                for (int tt = 0; tt < 4; ++tt) {
                    int row = tt * 16 + l16;
                    short8 xf = *(const short8*)(XsB + row * 1024 + ((s * 64 + lg * 16) ^ swz));
                    Hacc[0][tt] = MFMA16(a0, xf, Hacc[0][tt]);
                    Hacc[1][tt] = MFMA16(a1, xf, Hacc[1][tt]);
                }
                __syncthreads();
            }
            // ---- GELU -> Hs (b64 packed, R4-proven layout) ----
#pragma unroll
            for (int ft = 0; ft < 2; ++ft)
#pragma unroll
            for (int tt = 0; tt < 4; ++tt) {
                f32x4 h = Hacc[ft][tt];
                unsigned long long pk = 0;
#pragma unroll
                for (int r = 0; r < 4; ++r) {
                    float g = gelu_f(h[r]);
                    pk |= (unsigned long long)f2bf(g) << (r * 16);
                }
                int token = tt * 16 + l16;
                int f2 = wid * 64 + ft * 32 + lg * 8;   // f_local byte offset
                *(unsigned long long*)(HsB + token * 512 + (f2 ^ swz)) = pk;
            }
            __syncthreads();
            // ---- stage2: 16 phases, one W2 slab each (fs = u>>1, h = u&1) ----
#pragma unroll
            for (int u = 0; u < 16; ++u) {
                if (u < 15) issue_slab(fc, 17 + u);
                else        issue_slab((fc + 1) & (NFC - 1), 0);   // cross-fc / wrap (benign dead prefetch at tile end)
                const char* wb = Wring[u & 1];
                int fs = u >> 1, h = u & 1;
                int g0 = wid * 32 + l16;
                short8 b0 = wfrag(wb, g0);
                short8 b1 = wfrag(wb, g0 + 16);
#pragma unroll
                for (int tt = 0; tt < 4; ++tt) {
                    int row = tt * 16 + l16;
                    short8 af = *(const short8*)(HsB + row * 512 + ((fs * 64 + lg * 16) ^ swz));
                    Yacc[tt][h * 2 + 0] = MFMA16(af, b0, Yacc[tt][h * 2 + 0]);
                    Yacc[tt][h * 2 + 1] = MFMA16(af, b1, Yacc[tt][h * 2 + 1]);
                }
                __syncthreads();
            }
        }
        // ---- epilogue: scale + store ----
#pragma unroll
        for (int tt = 0; tt < 4; ++tt)
#pragma unroll
        for (int r = 0; r < 4; ++r) {
            int row = tt * 16 + lg * 4 + r;
            int idx = t0 + row;
            if (idx < cnt) {
                int entry = sl[idx];
                float wgt = wl[idx];
#pragma unroll
                for (int gt = 0; gt < 4; ++gt) {
                    int gcol = (gt >> 1) * 256 + wid * 32 + (gt & 1) * 16 + l16;
                    if constexpr (SLOT == 1) {
                        ybuf[(size_t)entry * DM + gcol] = f2bf(Yacc[tt][gt][r] * wgt);
                    } else {
                        atomAddF(out + (size_t)(entry >> 1) * DM + gcol, Yacc[tt][gt][r] * wgt);
                    }
                }
            }
        }
        __syncthreads();   // safe to restage Xs next tile
    }
}

// ---------------- combine: out[t] = Ybuf[2t] + Ybuf[2t+1] ----------------
__global__ __launch_bounds__(256)
void combine_kernel(const unsigned short* __restrict__ ybuf, float* __restrict__ out) {
    int gid = blockIdx.x * 256 + threadIdx.x;
    int t = gid >> 6, c8 = (gid & 63) * 8;
    const unsigned short* r0 = ybuf + ((size_t)t * 2) * DM + c8;
    short8 a = *(const short8*)r0;
    short8 b = *(const short8*)(r0 + DM);
    float* o = out + (size_t)t * DM + c8;
    f32x4 v0, v1;
    v0.x = bf2f((unsigned short)a[0]) + bf2f((unsigned short)b[0]);
    v0.y = bf2f((unsigned short)a[1]) + bf2f((unsigned short)b[1]);
    v0.z = bf2f((unsigned short)a[2]) + bf2f((unsigned short)b[2]);
    v0.w = bf2f((unsigned short)a[3]) + bf2f((unsigned short)b[3]);
    v1.x = bf2f((unsigned short)a[4]) + bf2f((unsigned short)b[4]);
    v1.y = bf2f((unsigned short)a[5]) + bf2f((unsigned short)b[5]);
    v1.z = bf2f((unsigned short)a[6]) + bf2f((unsigned short)b[6]);
    v1.w = bf2f((unsigned short)a[7]) + bf2f((unsigned short)b[7]);
    *(f32x4*)o = v0;
    *(f32x4*)(o + 4) = v1;
}

extern "C" void kernel_launch(void* const* d_in, const int* in_sizes, int n_in,
                              void* d_out, int out_size, void* d_ws, size_t ws_size,
                              hipStream_t stream) {
    const float* x  = (const float*)d_in[0];
    const float* gw = (const float*)d_in[1];
    const float* w1 = (const float*)d_in[2];
    const float* w2 = (const float*)d_in[3];
    float* out = (float*)d_out;
    char* ws = (char*)d_ws;

    const size_t W1N = (size_t)NE * DFF * DM;
    const size_t W2N = (size_t)NE * DM * DFF;
    unsigned short* w1b = (unsigned short*)ws;
    unsigned short* w2b = w1b + W1N;
    size_t off = (W1N + W2N) * 2;                       // 32 MiB
    int*   cursor   = (int*)(ws + off);   off += 256;
    int*   slotlist = (int*)(ws + off);   off += (size_t)NE * T_TOKENS * 4;
    float* wgtlist  = (float*)(ws + off); off += (size_t)NE * T_TOKENS * 4;
    float* entPart  = (float*)(ws + off); off += 8192;
    unsigned short* xbb = (unsigned short*)(ws + off); off += (size_t)T_TOKENS * DM * 2;
    size_t needB = off;
    unsigned short* ybuf = (unsigned short*)(ws + off); off += (size_t)T_TOKENS * 2 * DM * 2;
    size_t needA = off;

    int tier = (ws_size >= needA) ? 2 : ((ws_size >= needB) ? 1 : 0);

    hipMemsetAsync(cursor, 0, 64, stream);
    if (tier < 2) hipMemsetAsync(out, 0, RL_OFF * sizeof(float), stream);

    cvt_kernel<<<2048, 256, 0, stream>>>(w1, w1b, W1N / 4);
    cvt_kernel<<<2048, 256, 0, stream>>>(w2, w2b, W2N / 4);

    router_kernel<<<T_TOKENS / 16, 1024, 0, stream>>>(x, gw, out, cursor, slotlist, wgtlist,
                                                      entPart, tier >= 1 ? xbb : nullptr);
    ent_reduce<<<1, 1024, 0, stream>>>(entPart, out);

    if (tier == 2) {
        ffn_kernel<1, 1><<<NE * 64, 512, 0, stream>>>(x, xbb, w1b, w2b, cursor, slotlist, wgtlist, ybuf, out);
        combine_kernel<<<(T_TOKENS * DM / 8) / 256, 256, 0, stream>>>(ybuf, out);
    } else if (tier == 1) {
        ffn_kernel<1, 0><<<NE * 64, 512, 0, stream>>>(x, xbb, w1b, w2b, cursor, slotlist, wgtlist, nullptr, out);
    } else {
        ffn_kernel<0, 0><<<NE * 64, 512, 0, stream>>>(x, nullptr, w1b, w2b, cursor, slotlist, wgtlist, nullptr, out);
    }
}